// Round 19
// baseline (64.382 us; speedup 1.0000x reference)
//
#include <hip/hip_runtime.h>
#include <math.h>

constexpr int B_ = 4096, T_ = 200, D_ = 64, NT = 256;
constexpr float LOG2E = 1.4426950408889634f;

typedef __attribute__((ext_vector_type(8))) __bf16 bf16x8;
typedef __attribute__((ext_vector_type(4))) float f32x4;

__device__ __host__ inline unsigned short f2b_rne(float x) {
    unsigned u = __builtin_bit_cast(unsigned, x);
    u += 0x7FFF + ((u >> 16) & 1);
    return (unsigned short)(u >> 16);
}

__device__ inline unsigned short b16bits(float x) {
    return __builtin_bit_cast(unsigned short, (__bf16)x);
}

__device__ inline float frcp(float x) { return __builtin_amdgcn_rcpf(x); }

__device__ inline float fexp2(float x) {
#if __has_builtin(__builtin_amdgcn_exp2f)
    return __builtin_amdgcn_exp2f(x);
#else
    return exp2f(x);
#endif
}

__device__ inline bf16x8 pack8(float4 lo, float4 hi) {
    bf16x8 r;
    r[0] = (__bf16)lo.x; r[1] = (__bf16)lo.y; r[2] = (__bf16)lo.z; r[3] = (__bf16)lo.w;
    r[4] = (__bf16)hi.x; r[5] = (__bf16)hi.y; r[6] = (__bf16)hi.z; r[7] = (__bf16)hi.w;
    return r;
}

// ---------------------------------------------------------------------------
// Fold weights into MFMA-fragment order (bf16), PRE-SCALED by log2(e).
// ---------------------------------------------------------------------------
__global__ void fold_weights(const float* __restrict__ W1,
                             const float* __restrict__ W2,
                             unsigned short* __restrict__ w1f,
                             unsigned short* __restrict__ w2f,
                             unsigned short* __restrict__ wqff) {
    int i = blockIdx.x * blockDim.x + threadIdx.x;
    if (i < 10240) {
        int j = i & 7, lane = (i >> 3) & 63, nt = (i >> 9) % 5, s = i / 2560;
        int k = s * 32 + (lane >> 4) * 8 + j;
        int n = nt * 16 + (lane & 15);
        float v = (k < 64) ? W1[(64 + k) * 80 + n] - W1[(128 + k) * 80 + n]
                           : W1[(192 + (k - 64)) * 80 + n];
        w1f[i] = f2b_rne(v * LOG2E);
    } else if (i < 14848) {
        int i2 = i - 10240;
        int j = i2 & 7, lane = (i2 >> 3) & 63, nt = (i2 >> 9) % 3, s = i2 / 1536;
        int k = s * 32 + (lane >> 4) * 8 + j;
        int n = nt * 16 + (lane & 15);
        float v = (k < 80 && n < 40) ? W2[k * 40 + n] * LOG2E : 0.f;
        w2f[i2] = f2b_rne(v);
    } else if (i < 19968) {
        int i3 = i - 14848;
        int j = i3 & 7, lane = (i3 >> 3) & 63, nt = (i3 >> 9) % 5, s = i3 / 2560;
        int d = s * 32 + (lane >> 4) * 8 + j;
        int n = nt * 16 + (lane & 15);
        wqff[i3] = f2b_rne((W1[d * 80 + n] + W1[(128 + d) * 80 + n]) * LOG2E);
    }
}

// ---------------------------------------------------------------------------
// Length-stratified row map. Counting-sort rows by len DESCENDING, then
// rowmap[i*4+w] = sorted[i + 1024*((w + (i>>8)) & 3)]:
//  - every 4-wave block holds one row from each length-quartile (block work
//    ~ constant), and under round-robin dispatch (256 blocks/sweep) each
//    SIMD also gets one row per quartile -> per-SIMD work ~ constant.
// Occupancy counter showed 21% time-avg vs 50% instantaneous = drain tail
// from unbalanced per-SIMD sums; this removes it with zero hot-loop cost.
// (Within-bucket order via LDS atomics: assignment varies run-to-run, but
//  per-row outputs are identical -> d_out deterministic.)
// ---------------------------------------------------------------------------
__global__ __launch_bounds__(256)
void build_rowmap(const int* __restrict__ klen, int* __restrict__ rowmap) {
    __shared__ int cnt[200];
    __shared__ int base[200];
    __shared__ unsigned int off[200];
    __shared__ short sorted_[B_];
    const int tid = threadIdx.x;
    if (tid < 200) { cnt[tid] = 0; off[tid] = 0; }
    __syncthreads();
    for (int i = tid; i < B_; i += 256)
        atomicAdd(&cnt[klen[i]], 1);
    __syncthreads();
    if (tid == 0) {
        int acc = 0;
        for (int len = 199; len >= 0; --len) { base[len] = acc; acc += cnt[len]; }
    }
    __syncthreads();
    for (int i = tid; i < B_; i += 256) {
        int ln = klen[i];
        int pos = base[ln] + (int)atomicAdd(&off[ln], 1u);
        sorted_[pos] = (short)i;
    }
    __syncthreads();
    for (int idx = tid; idx < B_; idx += 256) {
        int i = idx >> 2, w = idx & 3;
        int role = (w + (i >> 8)) & 3;
        rowmap[idx] = (int)sorted_[i + 1024 * role];
    }
}

// ---------------------------------------------------------------------------
// Main kernel: round-16 fused-PV structure (verified 56.2us), one wave = one
// batch row via rowmap indirection. Barrier-free, W_eff in registers, 2-tile
// pipeline, exp2-sigmoid, no-rescale softmax (logits bounded), fused PV.
// ---------------------------------------------------------------------------
__global__ __launch_bounds__(NT, 2)
void din_attn(const float* __restrict__ q, const float* __restrict__ keys,
              const int* __restrict__ klen, const int* __restrict__ rowmap,
              const unsigned short* __restrict__ w1f,
              const unsigned short* __restrict__ w2f,
              const unsigned short* __restrict__ wqff,
              const float* __restrict__ b1, const float* __restrict__ b2,
              const float* __restrict__ W3, const float* __restrict__ b3,
              float* __restrict__ out) {
    const int tid = threadIdx.x;
    const int l = tid & 63, wid = tid >> 6, g4 = l >> 4, ln = l & 15;
    const int b = rowmap[blockIdx.x * 4 + wid];

    alignas(16) __shared__ unsigned short h1c[4][2][16 * 104]; // 26.6 KB dbuf
    __shared__ float olds[4][64];                              // 1 KB staging

    const int len = klen[b];
    const int ntile = (len + 15) >> 4;        // 0..13 active tiles
    const float* kb = keys + (size_t)b * 200 * 64;

    // ---- len==0: all logits equal -> uniform attn = mean of all 200 keys
    if (ntile == 0) {
        float4 oq = {0.f, 0.f, 0.f, 0.f};
        #pragma unroll 4
        for (int t = g4; t < 200; t += 4) {
            float4 kv = *(const float4*)(kb + t * 64 + 4 * ln);
            oq.x += kv.x; oq.y += kv.y; oq.z += kv.z; oq.w += kv.w;
        }
        oq.x += __shfl_xor(oq.x, 16); oq.x += __shfl_xor(oq.x, 32);
        oq.y += __shfl_xor(oq.y, 16); oq.y += __shfl_xor(oq.y, 32);
        oq.z += __shfl_xor(oq.z, 16); oq.z += __shfl_xor(oq.z, 32);
        oq.w += __shfl_xor(oq.w, 16); oq.w += __shfl_xor(oq.w, 32);
        if (g4 == 0) {
            oq.x *= 0.005f; oq.y *= 0.005f; oq.z *= 0.005f; oq.w *= 0.005f;
            *(float4*)(out + b * 64 + 4 * ln) = oq;
        }
        return;
    }

    unsigned short* buf0 = h1c[wid][0];
    unsigned short* buf1 = h1c[wid][1];
    #pragma unroll
    for (int r = 0; r < 4; ++r) {             // zero pad cols 80..95 once
        buf0[(g4 * 4 + r) * 104 + 80 + ln] = 0;
        buf1[(g4 * 4 + r) * 104 + 80 + ln] = 0;
    }

    const float b3v = b3[0];

#define LOADK(tile_, B0_, B1_, B2_, B3_) do {                              \
        int t_ = (tile_) * 16 + ln;                                        \
        int tc_ = t_ < 200 ? t_ : 199;                                     \
        const float* row_ = kb + tc_ * 64 + g4 * 8;                        \
        B0_ = *(const float4*)(row_);                                      \
        B1_ = *(const float4*)(row_ + 4);                                  \
        B2_ = *(const float4*)(row_ + 32);                                 \
        B3_ = *(const float4*)(row_ + 36);                                 \
    } while (0)

    // issue first two tiles' keys early; prologue compute hides them
    float4 A0, A1, A2, A3, C0, C1, C2, C3;
    LOADK(0, A0, A1, A2, A3);
    LOADK(1, C0, C1, C2, C3);

    float b2v[3], w3v[3];
    #pragma unroll
    for (int nt = 0; nt < 3; ++nt) {
        int idx = nt * 16 + ln;
        b2v[nt] = (idx < 40) ? b2[idx] * LOG2E : 0.f;
        w3v[nt] = (idx < 40) ? W3[idx] : 0.f;
    }

    const float* qb = q + b * 64;
    float4 q0  = *(const float4*)(qb + g4 * 8);
    float4 q0b = *(const float4*)(qb + g4 * 8 + 4);
    float4 q1  = *(const float4*)(qb + 32 + g4 * 8);
    float4 q1b = *(const float4*)(qb + 32 + g4 * 8 + 4);
    bf16x8 qf0 = pack8(q0, q0b);
    bf16x8 qf1 = pack8(q1, q1b);

    // ---- hinit via 10 MFMA: all A rows = q => every acc row = hinit ----
    float hv[5];
    {
        f32x4 hacc[5];
        #pragma unroll
        for (int nt = 0; nt < 5; ++nt) {
            float bv = b1[nt * 16 + ln] * LOG2E;
            hacc[nt] = (f32x4){bv, bv, bv, bv};
        }
        #pragma unroll
        for (int nt = 0; nt < 5; ++nt) {
            bf16x8 f0 = *(const bf16x8*)&wqff[((0 * 5 + nt) * 64 + l) * 8];
            bf16x8 f1 = *(const bf16x8*)&wqff[((1 * 5 + nt) * 64 + l) * 8];
            hacc[nt] = __builtin_amdgcn_mfma_f32_16x16x32_bf16(qf0, f0, hacc[nt], 0, 0, 0);
            hacc[nt] = __builtin_amdgcn_mfma_f32_16x16x32_bf16(qf1, f1, hacc[nt], 0, 0, 0);
        }
        #pragma unroll
        for (int nt = 0; nt < 5; ++nt) hv[nt] = hacc[nt][0];
    }

    // ---- W_eff = Wk + q (.) Wqk as 10 register B-frags (once/row) ----
    bf16x8 wf_[2][5];
    #pragma unroll
    for (int s = 0; s < 2; ++s) {
        float qa0 = (s == 0) ? q0.x  : q1.x,  qa1 = (s == 0) ? q0.y  : q1.y;
        float qa2 = (s == 0) ? q0.z  : q1.z,  qa3 = (s == 0) ? q0.w  : q1.w;
        float qb0 = (s == 0) ? q0b.x : q1b.x, qb1 = (s == 0) ? q0b.y : q1b.y;
        float qb2 = (s == 0) ? q0b.z : q1b.z, qb3 = (s == 0) ? q0b.w : q1b.w;
        #pragma unroll
        for (int nt = 0; nt < 5; ++nt) {
            bf16x8 wk = *(const bf16x8*)&w1f[((s * 5 + nt) * 64 + l) * 8];
            bf16x8 wq = *(const bf16x8*)&w1f[(((s + 2) * 5 + nt) * 64 + l) * 8];
            bf16x8 r;
            r[0] = (__bf16)fmaf(qa0, (float)wq[0], (float)wk[0]);
            r[1] = (__bf16)fmaf(qa1, (float)wq[1], (float)wk[1]);
            r[2] = (__bf16)fmaf(qa2, (float)wq[2], (float)wk[2]);
            r[3] = (__bf16)fmaf(qa3, (float)wq[3], (float)wk[3]);
            r[4] = (__bf16)fmaf(qb0, (float)wq[4], (float)wk[4]);
            r[5] = (__bf16)fmaf(qb1, (float)wq[5], (float)wk[5]);
            r[6] = (__bf16)fmaf(qb2, (float)wq[6], (float)wk[6]);
            r[7] = (__bf16)fmaf(qb3, (float)wq[7], (float)wk[7]);
            wf_[s][nt] = r;
        }
    }

    // softmax/PV accumulators (no-rescale: logits bounded, exp2 in [0.8,1.3])
    float s_part = 0.f;
    float4 o0 = {0,0,0,0}, o1 = o0, o2 = o0, o3 = o0;
    float e0_, e1_, e2_, e3_;

#define L1SIG(K0_, K1_, K2_, K3_, DST_) do {                               \
        f32x4 acc[5];                                                      \
        _Pragma("unroll")                                                  \
        for (int nt = 0; nt < 5; ++nt)                                     \
            acc[nt] = (f32x4){hv[nt], hv[nt], hv[nt], hv[nt]};             \
        bf16x8 av0 = pack8(K0_, K1_);                                      \
        bf16x8 av1 = pack8(K2_, K3_);                                      \
        _Pragma("unroll")                                                  \
        for (int nt = 0; nt < 5; ++nt) {                                   \
            acc[nt] = __builtin_amdgcn_mfma_f32_16x16x32_bf16(             \
                av0, wf_[0][nt], acc[nt], 0, 0, 0);                        \
            acc[nt] = __builtin_amdgcn_mfma_f32_16x16x32_bf16(             \
                av1, wf_[1][nt], acc[nt], 0, 0, 0);                        \
        }                                                                  \
        _Pragma("unroll")                                                  \
        for (int nt = 0; nt < 5; ++nt)                                     \
            _Pragma("unroll")                                              \
            for (int r = 0; r < 4; ++r) {                                  \
                float sg = frcp(1.f + fexp2(-acc[nt][r]));                 \
                (DST_)[(g4 * 4 + r) * 104 + nt * 16 + ln] = b16bits(sg);   \
            }                                                              \
    } while (0)

#define AFREAD(SRC_) do {                                                  \
        af0 = *(const bf16x8*)((SRC_) + ln * 104 + g4 * 8);                \
        af1 = *(const bf16x8*)((SRC_) + ln * 104 + 32 + g4 * 8);           \
        af2 = *(const bf16x8*)((SRC_) + ln * 104 + 64 + g4 * 8);           \
    } while (0)

#define L3E(tile_, r_, ER_) do {                                           \
        float p_ = w3v[0] * frcp(1.f + fexp2(-acc2[0][r_]))                \
                 + w3v[1] * frcp(1.f + fexp2(-acc2[1][r_]))                \
                 + w3v[2] * frcp(1.f + fexp2(-acc2[2][r_]));               \
        p_ += __shfl_xor(p_, 1); p_ += __shfl_xor(p_, 2);                  \
        p_ += __shfl_xor(p_, 4); p_ += __shfl_xor(p_, 8);                  \
        int trow_ = (tile_) * 16 + g4 * 4 + (r_);                          \
        ER_ = (trow_ < len)                                                \
            ? fexp2((p_ + b3v) * (0.125f * LOG2E)) : 0.f;                  \
    } while (0)

#define L2L3E(tile_) do {                                                  \
        f32x4 acc2[3];                                                     \
        _Pragma("unroll")                                                  \
        for (int nt = 0; nt < 3; ++nt)                                     \
            acc2[nt] = (f32x4){b2v[nt], b2v[nt], b2v[nt], b2v[nt]};        \
        _Pragma("unroll")                                                  \
        for (int nt = 0; nt < 3; ++nt) {                                   \
            bf16x8 w0_ = *(const bf16x8*)(w2f + ((0 * 3 + nt) * 64 + l) * 8); \
            bf16x8 w1_ = *(const bf16x8*)(w2f + ((1 * 3 + nt) * 64 + l) * 8); \
            bf16x8 w2_ = *(const bf16x8*)(w2f + ((2 * 3 + nt) * 64 + l) * 8); \
            acc2[nt] = __builtin_amdgcn_mfma_f32_16x16x32_bf16(af0, w0_, acc2[nt], 0, 0, 0); \
            acc2[nt] = __builtin_amdgcn_mfma_f32_16x16x32_bf16(af1, w1_, acc2[nt], 0, 0, 0); \
            acc2[nt] = __builtin_amdgcn_mfma_f32_16x16x32_bf16(af2, w2_, acc2[nt], 0, 0, 0); \
        }                                                                  \
        L3E(tile_, 0, e0_); L3E(tile_, 1, e1_);                            \
        L3E(tile_, 2, e2_); L3E(tile_, 3, e3_);                            \
    } while (0)

    // PV update: s += e's; route e[row=ln] to this lane with ONE bpermute
#define UPDATE(K0_, K1_, K2_, K3_) do {                                    \
        s_part += (e0_ + e1_) + (e2_ + e3_);                               \
        int rr_ = ln & 3;                                                  \
        float em_ = rr_ == 0 ? e0_ : rr_ == 1 ? e1_                        \
                  : rr_ == 2 ? e2_ : e3_;                                  \
        float pm_ = __shfl(em_, ((ln >> 2) << 4) + rr_);                   \
        o0.x = fmaf(pm_, K0_.x, o0.x); o0.y = fmaf(pm_, K0_.y, o0.y);      \
        o0.z = fmaf(pm_, K0_.z, o0.z); o0.w = fmaf(pm_, K0_.w, o0.w);      \
        o1.x = fmaf(pm_, K1_.x, o1.x); o1.y = fmaf(pm_, K1_.y, o1.y);      \
        o1.z = fmaf(pm_, K1_.z, o1.z); o1.w = fmaf(pm_, K1_.w, o1.w);      \
        o2.x = fmaf(pm_, K2_.x, o2.x); o2.y = fmaf(pm_, K2_.y, o2.y);      \
        o2.z = fmaf(pm_, K2_.z, o2.z); o2.w = fmaf(pm_, K2_.w, o2.w);      \
        o3.x = fmaf(pm_, K3_.x, o3.x); o3.y = fmaf(pm_, K3_.y, o3.y);      \
        o3.z = fmaf(pm_, K3_.z, o3.z); o3.w = fmaf(pm_, K3_.w, o3.w);      \
    } while (0)

    // ---- fused pipeline: L1SIG(it+1) hides AFREAD(it) LDS latency;
    //      keys(it) stay live through UPDATE(it), slot refilled after ----
    bf16x8 af0, af1, af2;
    L1SIG(A0, A1, A2, A3, buf0);           // h1(0); A = keys(0) stays live
    if (ntile > 1) {
        int it = 0;
        #pragma unroll 1
        while (it + 2 < ntile) {
            AFREAD(buf0);                  // h1(it)
            L1SIG(C0, C1, C2, C3, buf1);   // h1(it+1)
            L2L3E(it);
            UPDATE(A0, A1, A2, A3);        // keys(it) consumed
            LOADK(it + 2, A0, A1, A2, A3); // refill
            AFREAD(buf1);                  // h1(it+1)
            L1SIG(A0, A1, A2, A3, buf0);   // h1(it+2)
            L2L3E(it + 1);
            UPDATE(C0, C1, C2, C3);        // keys(it+1) consumed
            LOADK(it + 3, C0, C1, C2, C3); // over-prefetch clamped
            it += 2;
        }
        if (ntile - it == 2) {
            AFREAD(buf0);
            L1SIG(C0, C1, C2, C3, buf1);
            L2L3E(it);
            UPDATE(A0, A1, A2, A3);
            AFREAD(buf1);
            L2L3E(it + 1);
            UPDATE(C0, C1, C2, C3);
        } else {   // one tile left
            AFREAD(buf0);
            L2L3E(it);
            UPDATE(A0, A1, A2, A3);
        }
    } else {
        AFREAD(buf0);
        L2L3E(0);
        UPDATE(A0, A1, A2, A3);
    }
#undef LOADK
#undef L1SIG
#undef AFREAD
#undef L3E
#undef L2L3E
#undef UPDATE

    // ---- epilogue: normalize and reduce ----
    float s_tot = s_part;
    s_tot += __shfl_xor(s_tot, 16);
    s_tot += __shfl_xor(s_tot, 32);
    const float inv = frcp(s_tot);

#define RED16(x_) { x_ += __shfl_xor(x_, 1); x_ += __shfl_xor(x_, 2);      \
                    x_ += __shfl_xor(x_, 4); x_ += __shfl_xor(x_, 8); }
    RED16(o0.x) RED16(o0.y) RED16(o0.z) RED16(o0.w)
    RED16(o1.x) RED16(o1.y) RED16(o1.z) RED16(o1.w)
    RED16(o2.x) RED16(o2.y) RED16(o2.z) RED16(o2.w)
    RED16(o3.x) RED16(o3.y) RED16(o3.z) RED16(o3.w)
#undef RED16
    if (ln == 0) {
        float* od = olds[wid];
        od[g4 * 8 + 0] = o0.x; od[g4 * 8 + 1] = o0.y;
        od[g4 * 8 + 2] = o0.z; od[g4 * 8 + 3] = o0.w;
        od[g4 * 8 + 4] = o1.x; od[g4 * 8 + 5] = o1.y;
        od[g4 * 8 + 6] = o1.z; od[g4 * 8 + 7] = o1.w;
        od[32 + g4 * 8 + 0] = o2.x; od[32 + g4 * 8 + 1] = o2.y;
        od[32 + g4 * 8 + 2] = o2.z; od[32 + g4 * 8 + 3] = o2.w;
        od[32 + g4 * 8 + 4] = o3.x; od[32 + g4 * 8 + 5] = o3.y;
        od[32 + g4 * 8 + 6] = o3.z; od[32 + g4 * 8 + 7] = o3.w;
    }
    // same-wave LDS RAW: ds ops in order per wave (round-7-verified pattern)
    out[b * 64 + l] = olds[wid][l] * inv;
}

extern "C" void kernel_launch(void* const* d_in, const int* in_sizes, int n_in,
                              void* d_out, int out_size, void* d_ws, size_t ws_size,
                              hipStream_t stream) {
    const float* q    = (const float*)d_in[0];
    const float* keys = (const float*)d_in[1];
    const int*   kl   = (const int*)d_in[2];
    const float* W1   = (const float*)d_in[3];
    const float* b1   = (const float*)d_in[4];
    const float* W2   = (const float*)d_in[5];
    const float* b2   = (const float*)d_in[6];
    const float* W3   = (const float*)d_in[7];
    const float* b3   = (const float*)d_in[8];

    unsigned short* w1f  = (unsigned short*)d_ws;           // 10240 bf16
    unsigned short* w2f  = w1f + 10240;                     //  4608 bf16
    unsigned short* wqff = w2f + 4608;                      //  5120 bf16
    int* rowmap = (int*)((char*)d_ws + 49152);              //  4096 int

    fold_weights<<<(19968 + 255) / 256, 256, 0, stream>>>(W1, W2, w1f, w2f, wqff);
    build_rowmap<<<1, 256, 0, stream>>>(kl, rowmap);
    din_attn<<<B_ / 4, NT, 0, stream>>>(q, keys, kl, rowmap, w1f, w2f, wqff,
                                        b1, b2, W3, b3, (float*)d_out);
}

// Round 20
// 58.808 us; speedup vs baseline: 1.0948x; 1.0948x over previous
//
#include <hip/hip_runtime.h>
#include <math.h>

constexpr int B_ = 4096, T_ = 200, D_ = 64, NT = 256;
constexpr float LOG2E = 1.4426950408889634f;

typedef __attribute__((ext_vector_type(8))) __bf16 bf16x8;
typedef __attribute__((ext_vector_type(4))) float f32x4;

__device__ __host__ inline unsigned short f2b_rne(float x) {
    unsigned u = __builtin_bit_cast(unsigned, x);
    u += 0x7FFF + ((u >> 16) & 1);
    return (unsigned short)(u >> 16);
}

__device__ inline unsigned short b16bits(float x) {
    return __builtin_bit_cast(unsigned short, (__bf16)x);
}

__device__ inline float frcp(float x) { return __builtin_amdgcn_rcpf(x); }

__device__ inline float fexp2(float x) {
#if __has_builtin(__builtin_amdgcn_exp2f)
    return __builtin_amdgcn_exp2f(x);
#else
    return exp2f(x);
#endif
}

__device__ inline bf16x8 pack8(float4 lo, float4 hi) {
    bf16x8 r;
    r[0] = (__bf16)lo.x; r[1] = (__bf16)lo.y; r[2] = (__bf16)lo.z; r[3] = (__bf16)lo.w;
    r[4] = (__bf16)hi.x; r[5] = (__bf16)hi.y; r[6] = (__bf16)hi.z; r[7] = (__bf16)hi.w;
    return r;
}

// ---------------------------------------------------------------------------
// Fold weights into MFMA-fragment order (bf16), PRE-SCALED by log2(e).
// ---------------------------------------------------------------------------
__global__ void fold_weights(const float* __restrict__ W1,
                             const float* __restrict__ W2,
                             unsigned short* __restrict__ w1f,
                             unsigned short* __restrict__ w2f,
                             unsigned short* __restrict__ wqff) {
    int i = blockIdx.x * blockDim.x + threadIdx.x;
    if (i < 10240) {
        int j = i & 7, lane = (i >> 3) & 63, nt = (i >> 9) % 5, s = i / 2560;
        int k = s * 32 + (lane >> 4) * 8 + j;
        int n = nt * 16 + (lane & 15);
        float v = (k < 64) ? W1[(64 + k) * 80 + n] - W1[(128 + k) * 80 + n]
                           : W1[(192 + (k - 64)) * 80 + n];
        w1f[i] = f2b_rne(v * LOG2E);
    } else if (i < 14848) {
        int i2 = i - 10240;
        int j = i2 & 7, lane = (i2 >> 3) & 63, nt = (i2 >> 9) % 3, s = i2 / 1536;
        int k = s * 32 + (lane >> 4) * 8 + j;
        int n = nt * 16 + (lane & 15);
        float v = (k < 80 && n < 40) ? W2[k * 40 + n] * LOG2E : 0.f;
        w2f[i2] = f2b_rne(v);
    } else if (i < 19968) {
        int i3 = i - 14848;
        int j = i3 & 7, lane = (i3 >> 3) & 63, nt = (i3 >> 9) % 5, s = i3 / 2560;
        int d = s * 32 + (lane >> 4) * 8 + j;
        int n = nt * 16 + (lane & 15);
        wqff[i3] = f2b_rne((W1[d * 80 + n] + W1[(128 + d) * 80 + n]) * LOG2E);
    }
}

// ---------------------------------------------------------------------------
// Main kernel: round-18 structure verbatim (verified 56.15us twice) +
// s_setprio(1) around the MFMA clusters (T5): independent per-wave rows at
// different phases = the regime where setprio measured +4-7% (attn, m191).
// r19's rowmap/sort reverted (serial sort kernel on critical path + keys
// scatter: 56.2 -> 64.4).
// ---------------------------------------------------------------------------
__global__ __launch_bounds__(NT, 2)
void din_attn(const float* __restrict__ q, const float* __restrict__ keys,
              const int* __restrict__ klen,
              const unsigned short* __restrict__ w1f,
              const unsigned short* __restrict__ w2f,
              const unsigned short* __restrict__ wqff,
              const float* __restrict__ b1, const float* __restrict__ b2,
              const float* __restrict__ W3, const float* __restrict__ b3,
              float* __restrict__ out) {
    const int tid = threadIdx.x;
    const int l = tid & 63, wid = tid >> 6, g4 = l >> 4, ln = l & 15;
    const int b = blockIdx.x * 4 + wid;

    alignas(16) __shared__ unsigned short h1c[4][2][16 * 104]; // 26.6 KB dbuf
    __shared__ float olds[4][64];                              // 1 KB staging

    const int len = klen[b];
    const int ntile = (len + 15) >> 4;        // 0..13 active tiles
    const float* kb = keys + (size_t)b * 200 * 64;

    // ---- len==0: all logits equal -> uniform attn = mean of all 200 keys
    if (ntile == 0) {
        float4 oq = {0.f, 0.f, 0.f, 0.f};
        #pragma unroll 4
        for (int t = g4; t < 200; t += 4) {
            float4 kv = *(const float4*)(kb + t * 64 + 4 * ln);
            oq.x += kv.x; oq.y += kv.y; oq.z += kv.z; oq.w += kv.w;
        }
        oq.x += __shfl_xor(oq.x, 16); oq.x += __shfl_xor(oq.x, 32);
        oq.y += __shfl_xor(oq.y, 16); oq.y += __shfl_xor(oq.y, 32);
        oq.z += __shfl_xor(oq.z, 16); oq.z += __shfl_xor(oq.z, 32);
        oq.w += __shfl_xor(oq.w, 16); oq.w += __shfl_xor(oq.w, 32);
        if (g4 == 0) {
            oq.x *= 0.005f; oq.y *= 0.005f; oq.z *= 0.005f; oq.w *= 0.005f;
            *(float4*)(out + b * 64 + 4 * ln) = oq;
        }
        return;
    }

    unsigned short* buf0 = h1c[wid][0];
    unsigned short* buf1 = h1c[wid][1];
    #pragma unroll
    for (int r = 0; r < 4; ++r) {             // zero pad cols 80..95 once
        buf0[(g4 * 4 + r) * 104 + 80 + ln] = 0;
        buf1[(g4 * 4 + r) * 104 + 80 + ln] = 0;
    }

    const float b3v = b3[0];

#define LOADK(tile_, B0_, B1_, B2_, B3_) do {                              \
        int t_ = (tile_) * 16 + ln;                                        \
        int tc_ = t_ < 200 ? t_ : 199;                                     \
        const float* row_ = kb + tc_ * 64 + g4 * 8;                        \
        B0_ = *(const float4*)(row_);                                      \
        B1_ = *(const float4*)(row_ + 4);                                  \
        B2_ = *(const float4*)(row_ + 32);                                 \
        B3_ = *(const float4*)(row_ + 36);                                 \
    } while (0)

    // issue first two tiles' keys early; prologue compute hides them
    float4 A0, A1, A2, A3, C0, C1, C2, C3;
    LOADK(0, A0, A1, A2, A3);
    LOADK(1, C0, C1, C2, C3);

    float b2v[3], w3v[3];
    #pragma unroll
    for (int nt = 0; nt < 3; ++nt) {
        int idx = nt * 16 + ln;
        b2v[nt] = (idx < 40) ? b2[idx] * LOG2E : 0.f;
        w3v[nt] = (idx < 40) ? W3[idx] : 0.f;
    }

    const float* qb = q + b * 64;
    float4 q0  = *(const float4*)(qb + g4 * 8);
    float4 q0b = *(const float4*)(qb + g4 * 8 + 4);
    float4 q1  = *(const float4*)(qb + 32 + g4 * 8);
    float4 q1b = *(const float4*)(qb + 32 + g4 * 8 + 4);
    bf16x8 qf0 = pack8(q0, q0b);
    bf16x8 qf1 = pack8(q1, q1b);

    // ---- hinit via 10 MFMA: all A rows = q => every acc row = hinit ----
    float hv[5];
    {
        f32x4 hacc[5];
        #pragma unroll
        for (int nt = 0; nt < 5; ++nt) {
            float bv = b1[nt * 16 + ln] * LOG2E;
            hacc[nt] = (f32x4){bv, bv, bv, bv};
        }
        #pragma unroll
        for (int nt = 0; nt < 5; ++nt) {
            bf16x8 f0 = *(const bf16x8*)&wqff[((0 * 5 + nt) * 64 + l) * 8];
            bf16x8 f1 = *(const bf16x8*)&wqff[((1 * 5 + nt) * 64 + l) * 8];
            hacc[nt] = __builtin_amdgcn_mfma_f32_16x16x32_bf16(qf0, f0, hacc[nt], 0, 0, 0);
            hacc[nt] = __builtin_amdgcn_mfma_f32_16x16x32_bf16(qf1, f1, hacc[nt], 0, 0, 0);
        }
        #pragma unroll
        for (int nt = 0; nt < 5; ++nt) hv[nt] = hacc[nt][0];
    }

    // ---- W_eff = Wk + q (.) Wqk as 10 register B-frags (once/row) ----
    bf16x8 wf_[2][5];
    #pragma unroll
    for (int s = 0; s < 2; ++s) {
        float qa0 = (s == 0) ? q0.x  : q1.x,  qa1 = (s == 0) ? q0.y  : q1.y;
        float qa2 = (s == 0) ? q0.z  : q1.z,  qa3 = (s == 0) ? q0.w  : q1.w;
        float qb0 = (s == 0) ? q0b.x : q1b.x, qb1 = (s == 0) ? q0b.y : q1b.y;
        float qb2 = (s == 0) ? q0b.z : q1b.z, qb3 = (s == 0) ? q0b.w : q1b.w;
        #pragma unroll
        for (int nt = 0; nt < 5; ++nt) {
            bf16x8 wk = *(const bf16x8*)&w1f[((s * 5 + nt) * 64 + l) * 8];
            bf16x8 wq = *(const bf16x8*)&w1f[(((s + 2) * 5 + nt) * 64 + l) * 8];
            bf16x8 r;
            r[0] = (__bf16)fmaf(qa0, (float)wq[0], (float)wk[0]);
            r[1] = (__bf16)fmaf(qa1, (float)wq[1], (float)wk[1]);
            r[2] = (__bf16)fmaf(qa2, (float)wq[2], (float)wk[2]);
            r[3] = (__bf16)fmaf(qa3, (float)wq[3], (float)wk[3]);
            r[4] = (__bf16)fmaf(qb0, (float)wq[4], (float)wk[4]);
            r[5] = (__bf16)fmaf(qb1, (float)wq[5], (float)wk[5]);
            r[6] = (__bf16)fmaf(qb2, (float)wq[6], (float)wk[6]);
            r[7] = (__bf16)fmaf(qb3, (float)wq[7], (float)wk[7]);
            wf_[s][nt] = r;
        }
    }

    // softmax/PV accumulators (no-rescale: logits bounded, exp2 in [0.8,1.3])
    float s_part = 0.f;
    float4 o0 = {0,0,0,0}, o1 = o0, o2 = o0, o3 = o0;
    float e0_, e1_, e2_, e3_;

#define L1SIG(K0_, K1_, K2_, K3_, DST_) do {                               \
        f32x4 acc[5];                                                      \
        _Pragma("unroll")                                                  \
        for (int nt = 0; nt < 5; ++nt)                                     \
            acc[nt] = (f32x4){hv[nt], hv[nt], hv[nt], hv[nt]};             \
        bf16x8 av0 = pack8(K0_, K1_);                                      \
        bf16x8 av1 = pack8(K2_, K3_);                                      \
        __builtin_amdgcn_s_setprio(1);                                     \
        _Pragma("unroll")                                                  \
        for (int nt = 0; nt < 5; ++nt) {                                   \
            acc[nt] = __builtin_amdgcn_mfma_f32_16x16x32_bf16(             \
                av0, wf_[0][nt], acc[nt], 0, 0, 0);                        \
            acc[nt] = __builtin_amdgcn_mfma_f32_16x16x32_bf16(             \
                av1, wf_[1][nt], acc[nt], 0, 0, 0);                        \
        }                                                                  \
        __builtin_amdgcn_s_setprio(0);                                     \
        _Pragma("unroll")                                                  \
        for (int nt = 0; nt < 5; ++nt)                                     \
            _Pragma("unroll")                                              \
            for (int r = 0; r < 4; ++r) {                                  \
                float sg = frcp(1.f + fexp2(-acc[nt][r]));                 \
                (DST_)[(g4 * 4 + r) * 104 + nt * 16 + ln] = b16bits(sg);   \
            }                                                              \
    } while (0)

#define AFREAD(SRC_) do {                                                  \
        af0 = *(const bf16x8*)((SRC_) + ln * 104 + g4 * 8);                \
        af1 = *(const bf16x8*)((SRC_) + ln * 104 + 32 + g4 * 8);           \
        af2 = *(const bf16x8*)((SRC_) + ln * 104 + 64 + g4 * 8);           \
    } while (0)

#define L3E(tile_, r_, ER_) do {                                           \
        float p_ = w3v[0] * frcp(1.f + fexp2(-acc2[0][r_]))                \
                 + w3v[1] * frcp(1.f + fexp2(-acc2[1][r_]))                \
                 + w3v[2] * frcp(1.f + fexp2(-acc2[2][r_]));               \
        p_ += __shfl_xor(p_, 1); p_ += __shfl_xor(p_, 2);                  \
        p_ += __shfl_xor(p_, 4); p_ += __shfl_xor(p_, 8);                  \
        int trow_ = (tile_) * 16 + g4 * 4 + (r_);                          \
        ER_ = (trow_ < len)                                                \
            ? fexp2((p_ + b3v) * (0.125f * LOG2E)) : 0.f;                  \
    } while (0)

#define L2L3E(tile_) do {                                                  \
        f32x4 acc2[3];                                                     \
        _Pragma("unroll")                                                  \
        for (int nt = 0; nt < 3; ++nt)                                     \
            acc2[nt] = (f32x4){b2v[nt], b2v[nt], b2v[nt], b2v[nt]};        \
        __builtin_amdgcn_s_setprio(1);                                     \
        _Pragma("unroll")                                                  \
        for (int nt = 0; nt < 3; ++nt) {                                   \
            bf16x8 w0_ = *(const bf16x8*)(w2f + ((0 * 3 + nt) * 64 + l) * 8); \
            bf16x8 w1_ = *(const bf16x8*)(w2f + ((1 * 3 + nt) * 64 + l) * 8); \
            bf16x8 w2_ = *(const bf16x8*)(w2f + ((2 * 3 + nt) * 64 + l) * 8); \
            acc2[nt] = __builtin_amdgcn_mfma_f32_16x16x32_bf16(af0, w0_, acc2[nt], 0, 0, 0); \
            acc2[nt] = __builtin_amdgcn_mfma_f32_16x16x32_bf16(af1, w1_, acc2[nt], 0, 0, 0); \
            acc2[nt] = __builtin_amdgcn_mfma_f32_16x16x32_bf16(af2, w2_, acc2[nt], 0, 0, 0); \
        }                                                                  \
        __builtin_amdgcn_s_setprio(0);                                     \
        L3E(tile_, 0, e0_); L3E(tile_, 1, e1_);                            \
        L3E(tile_, 2, e2_); L3E(tile_, 3, e3_);                            \
    } while (0)

    // PV update: s += e's; route e[row=ln] to this lane with ONE bpermute
#define UPDATE(K0_, K1_, K2_, K3_) do {                                    \
        s_part += (e0_ + e1_) + (e2_ + e3_);                               \
        int rr_ = ln & 3;                                                  \
        float em_ = rr_ == 0 ? e0_ : rr_ == 1 ? e1_                        \
                  : rr_ == 2 ? e2_ : e3_;                                  \
        float pm_ = __shfl(em_, ((ln >> 2) << 4) + rr_);                   \
        o0.x = fmaf(pm_, K0_.x, o0.x); o0.y = fmaf(pm_, K0_.y, o0.y);      \
        o0.z = fmaf(pm_, K0_.z, o0.z); o0.w = fmaf(pm_, K0_.w, o0.w);      \
        o1.x = fmaf(pm_, K1_.x, o1.x); o1.y = fmaf(pm_, K1_.y, o1.y);      \
        o1.z = fmaf(pm_, K1_.z, o1.z); o1.w = fmaf(pm_, K1_.w, o1.w);      \
        o2.x = fmaf(pm_, K2_.x, o2.x); o2.y = fmaf(pm_, K2_.y, o2.y);      \
        o2.z = fmaf(pm_, K2_.z, o2.z); o2.w = fmaf(pm_, K2_.w, o2.w);      \
        o3.x = fmaf(pm_, K3_.x, o3.x); o3.y = fmaf(pm_, K3_.y, o3.y);      \
        o3.z = fmaf(pm_, K3_.z, o3.z); o3.w = fmaf(pm_, K3_.w, o3.w);      \
    } while (0)

    // ---- fused pipeline: L1SIG(it+1) hides AFREAD(it) LDS latency;
    //      keys(it) stay live through UPDATE(it), slot refilled after ----
    bf16x8 af0, af1, af2;
    L1SIG(A0, A1, A2, A3, buf0);           // h1(0); A = keys(0) stays live
    if (ntile > 1) {
        int it = 0;
        #pragma unroll 1
        while (it + 2 < ntile) {
            AFREAD(buf0);                  // h1(it)
            L1SIG(C0, C1, C2, C3, buf1);   // h1(it+1)
            L2L3E(it);
            UPDATE(A0, A1, A2, A3);        // keys(it) consumed
            LOADK(it + 2, A0, A1, A2, A3); // refill
            AFREAD(buf1);                  // h1(it+1)
            L1SIG(A0, A1, A2, A3, buf0);   // h1(it+2)
            L2L3E(it + 1);
            UPDATE(C0, C1, C2, C3);        // keys(it+1) consumed
            LOADK(it + 3, C0, C1, C2, C3); // over-prefetch clamped
            it += 2;
        }
        if (ntile - it == 2) {
            AFREAD(buf0);
            L1SIG(C0, C1, C2, C3, buf1);
            L2L3E(it);
            UPDATE(A0, A1, A2, A3);
            AFREAD(buf1);
            L2L3E(it + 1);
            UPDATE(C0, C1, C2, C3);
        } else {   // one tile left
            AFREAD(buf0);
            L2L3E(it);
            UPDATE(A0, A1, A2, A3);
        }
    } else {
        AFREAD(buf0);
        L2L3E(0);
        UPDATE(A0, A1, A2, A3);
    }
#undef LOADK
#undef L1SIG
#undef AFREAD
#undef L3E
#undef L2L3E
#undef UPDATE

    // ---- epilogue: normalize and reduce ----
    float s_tot = s_part;
    s_tot += __shfl_xor(s_tot, 16);
    s_tot += __shfl_xor(s_tot, 32);
    const float inv = frcp(s_tot);

#define RED16(x_) { x_ += __shfl_xor(x_, 1); x_ += __shfl_xor(x_, 2);      \
                    x_ += __shfl_xor(x_, 4); x_ += __shfl_xor(x_, 8); }
    RED16(o0.x) RED16(o0.y) RED16(o0.z) RED16(o0.w)
    RED16(o1.x) RED16(o1.y) RED16(o1.z) RED16(o1.w)
    RED16(o2.x) RED16(o2.y) RED16(o2.z) RED16(o2.w)
    RED16(o3.x) RED16(o3.y) RED16(o3.z) RED16(o3.w)
#undef RED16
    if (ln == 0) {
        float* od = olds[wid];
        od[g4 * 8 + 0] = o0.x; od[g4 * 8 + 1] = o0.y;
        od[g4 * 8 + 2] = o0.z; od[g4 * 8 + 3] = o0.w;
        od[g4 * 8 + 4] = o1.x; od[g4 * 8 + 5] = o1.y;
        od[g4 * 8 + 6] = o1.z; od[g4 * 8 + 7] = o1.w;
        od[32 + g4 * 8 + 0] = o2.x; od[32 + g4 * 8 + 1] = o2.y;
        od[32 + g4 * 8 + 2] = o2.z; od[32 + g4 * 8 + 3] = o2.w;
        od[32 + g4 * 8 + 4] = o3.x; od[32 + g4 * 8 + 5] = o3.y;
        od[32 + g4 * 8 + 6] = o3.z; od[32 + g4 * 8 + 7] = o3.w;
    }
    // same-wave LDS RAW: ds ops in order per wave (round-7-verified pattern)
    out[b * 64 + l] = olds[wid][l] * inv;
}

extern "C" void kernel_launch(void* const* d_in, const int* in_sizes, int n_in,
                              void* d_out, int out_size, void* d_ws, size_t ws_size,
                              hipStream_t stream) {
    const float* q    = (const float*)d_in[0];
    const float* keys = (const float*)d_in[1];
    const int*   kl   = (const int*)d_in[2];
    const float* W1   = (const float*)d_in[3];
    const float* b1   = (const float*)d_in[4];
    const float* W2   = (const float*)d_in[5];
    const float* b2   = (const float*)d_in[6];
    const float* W3   = (const float*)d_in[7];
    const float* b3   = (const float*)d_in[8];

    unsigned short* w1f  = (unsigned short*)d_ws;           // 10240 bf16
    unsigned short* w2f  = w1f + 10240;                     //  4608 bf16
    unsigned short* wqff = w2f + 4608;                      //  5120 bf16

    fold_weights<<<(19968 + 255) / 256, 256, 0, stream>>>(W1, W2, w1f, w2f, wqff);
    din_attn<<<B_ / 4, NT, 0, stream>>>(q, keys, kl, w1f, w2f, wqff, b1, b2,
                                        W3, b3, (float*)d_out);
}

// Round 21
// 56.024 us; speedup vs baseline: 1.1492x; 1.0497x over previous
//
#include <hip/hip_runtime.h>
#include <math.h>

constexpr int B_ = 4096, T_ = 200, D_ = 64, NT = 256;
constexpr float LOG2E = 1.4426950408889634f;

typedef __attribute__((ext_vector_type(8))) __bf16 bf16x8;
typedef __attribute__((ext_vector_type(4))) float f32x4;

__device__ __host__ inline unsigned short f2b_rne(float x) {
    unsigned u = __builtin_bit_cast(unsigned, x);
    u += 0x7FFF + ((u >> 16) & 1);
    return (unsigned short)(u >> 16);
}

__device__ inline unsigned short b16bits(float x) {
    return __builtin_bit_cast(unsigned short, (__bf16)x);
}

__device__ inline float frcp(float x) { return __builtin_amdgcn_rcpf(x); }

__device__ inline float fexp2(float x) {
#if __has_builtin(__builtin_amdgcn_exp2f)
    return __builtin_amdgcn_exp2f(x);
#else
    return exp2f(x);
#endif
}

__device__ inline bf16x8 pack8(float4 lo, float4 hi) {
    bf16x8 r;
    r[0] = (__bf16)lo.x; r[1] = (__bf16)lo.y; r[2] = (__bf16)lo.z; r[3] = (__bf16)lo.w;
    r[4] = (__bf16)hi.x; r[5] = (__bf16)hi.y; r[6] = (__bf16)hi.z; r[7] = (__bf16)hi.w;
    return r;
}

// ---------------------------------------------------------------------------
// Fold weights into MFMA-fragment order (bf16), PRE-SCALED by log2(e).
// ---------------------------------------------------------------------------
__global__ void fold_weights(const float* __restrict__ W1,
                             const float* __restrict__ W2,
                             unsigned short* __restrict__ w1f,
                             unsigned short* __restrict__ w2f,
                             unsigned short* __restrict__ wqff) {
    int i = blockIdx.x * blockDim.x + threadIdx.x;
    if (i < 10240) {
        int j = i & 7, lane = (i >> 3) & 63, nt = (i >> 9) % 5, s = i / 2560;
        int k = s * 32 + (lane >> 4) * 8 + j;
        int n = nt * 16 + (lane & 15);
        float v = (k < 64) ? W1[(64 + k) * 80 + n] - W1[(128 + k) * 80 + n]
                           : W1[(192 + (k - 64)) * 80 + n];
        w1f[i] = f2b_rne(v * LOG2E);
    } else if (i < 14848) {
        int i2 = i - 10240;
        int j = i2 & 7, lane = (i2 >> 3) & 63, nt = (i2 >> 9) % 3, s = i2 / 1536;
        int k = s * 32 + (lane >> 4) * 8 + j;
        int n = nt * 16 + (lane & 15);
        float v = (k < 80 && n < 40) ? W2[k * 40 + n] * LOG2E : 0.f;
        w2f[i2] = f2b_rne(v);
    } else if (i < 19968) {
        int i3 = i - 14848;
        int j = i3 & 7, lane = (i3 >> 3) & 63, nt = (i3 >> 9) % 5, s = i3 / 2560;
        int d = s * 32 + (lane >> 4) * 8 + j;
        int n = nt * 16 + (lane & 15);
        wqff[i3] = f2b_rne((W1[d * 80 + n] + W1[(128 + d) * 80 + n]) * LOG2E);
    }
}

// ---------------------------------------------------------------------------
// FINAL KERNEL (round-18 structure, verified 56.15us twice; 20.1x over the
// round-1 baseline). One wave = one batch row, barrier-free. Techniques:
//  - layers as bf16 MFMA; W_eff = Wk + q(.)Wqk folded into 10 register
//    B-frags per row (K halved to 64); hinit via 10 one-time MFMAs
//  - exp2-folded sigmoid (weights pre-scaled by log2e), v_rcp
//  - dynamic tile count ntile = ceil(len/16); fused PV (keys consumed in
//    registers, single keys read); no-rescale softmax (logits bounded)
//  - 2-tile pipeline: L1SIG(it+1) hides the h1 LDS round-trip of L2L3E(it)
// Plateau evidence: r14 backfill / r15,r17 deeper prefetch / r19 balance /
// r20 setprio all neutral-to-negative; chain is register-budget-bound.
// ---------------------------------------------------------------------------
__global__ __launch_bounds__(NT, 2)
void din_attn(const float* __restrict__ q, const float* __restrict__ keys,
              const int* __restrict__ klen,
              const unsigned short* __restrict__ w1f,
              const unsigned short* __restrict__ w2f,
              const unsigned short* __restrict__ wqff,
              const float* __restrict__ b1, const float* __restrict__ b2,
              const float* __restrict__ W3, const float* __restrict__ b3,
              float* __restrict__ out) {
    const int tid = threadIdx.x;
    const int l = tid & 63, wid = tid >> 6, g4 = l >> 4, ln = l & 15;
    const int b = blockIdx.x * 4 + wid;

    alignas(16) __shared__ unsigned short h1c[4][2][16 * 104]; // 26.6 KB dbuf
    __shared__ float olds[4][64];                              // 1 KB staging

    const int len = klen[b];
    const int ntile = (len + 15) >> 4;        // 0..13 active tiles
    const float* kb = keys + (size_t)b * 200 * 64;

    // ---- len==0: all logits equal -> uniform attn = mean of all 200 keys
    if (ntile == 0) {
        float4 oq = {0.f, 0.f, 0.f, 0.f};
        #pragma unroll 4
        for (int t = g4; t < 200; t += 4) {
            float4 kv = *(const float4*)(kb + t * 64 + 4 * ln);
            oq.x += kv.x; oq.y += kv.y; oq.z += kv.z; oq.w += kv.w;
        }
        oq.x += __shfl_xor(oq.x, 16); oq.x += __shfl_xor(oq.x, 32);
        oq.y += __shfl_xor(oq.y, 16); oq.y += __shfl_xor(oq.y, 32);
        oq.z += __shfl_xor(oq.z, 16); oq.z += __shfl_xor(oq.z, 32);
        oq.w += __shfl_xor(oq.w, 16); oq.w += __shfl_xor(oq.w, 32);
        if (g4 == 0) {
            oq.x *= 0.005f; oq.y *= 0.005f; oq.z *= 0.005f; oq.w *= 0.005f;
            *(float4*)(out + b * 64 + 4 * ln) = oq;
        }
        return;
    }

    unsigned short* buf0 = h1c[wid][0];
    unsigned short* buf1 = h1c[wid][1];
    #pragma unroll
    for (int r = 0; r < 4; ++r) {             // zero pad cols 80..95 once
        buf0[(g4 * 4 + r) * 104 + 80 + ln] = 0;
        buf1[(g4 * 4 + r) * 104 + 80 + ln] = 0;
    }

    const float b3v = b3[0];

#define LOADK(tile_, B0_, B1_, B2_, B3_) do {                              \
        int t_ = (tile_) * 16 + ln;                                        \
        int tc_ = t_ < 200 ? t_ : 199;                                     \
        const float* row_ = kb + tc_ * 64 + g4 * 8;                        \
        B0_ = *(const float4*)(row_);                                      \
        B1_ = *(const float4*)(row_ + 4);                                  \
        B2_ = *(const float4*)(row_ + 32);                                 \
        B3_ = *(const float4*)(row_ + 36);                                 \
    } while (0)

    // issue first two tiles' keys early; prologue compute hides them
    float4 A0, A1, A2, A3, C0, C1, C2, C3;
    LOADK(0, A0, A1, A2, A3);
    LOADK(1, C0, C1, C2, C3);

    float b2v[3], w3v[3];
    #pragma unroll
    for (int nt = 0; nt < 3; ++nt) {
        int idx = nt * 16 + ln;
        b2v[nt] = (idx < 40) ? b2[idx] * LOG2E : 0.f;
        w3v[nt] = (idx < 40) ? W3[idx] : 0.f;
    }

    const float* qb = q + b * 64;
    float4 q0  = *(const float4*)(qb + g4 * 8);
    float4 q0b = *(const float4*)(qb + g4 * 8 + 4);
    float4 q1  = *(const float4*)(qb + 32 + g4 * 8);
    float4 q1b = *(const float4*)(qb + 32 + g4 * 8 + 4);
    bf16x8 qf0 = pack8(q0, q0b);
    bf16x8 qf1 = pack8(q1, q1b);

    // ---- hinit via 10 MFMA: all A rows = q => every acc row = hinit ----
    float hv[5];
    {
        f32x4 hacc[5];
        #pragma unroll
        for (int nt = 0; nt < 5; ++nt) {
            float bv = b1[nt * 16 + ln] * LOG2E;
            hacc[nt] = (f32x4){bv, bv, bv, bv};
        }
        #pragma unroll
        for (int nt = 0; nt < 5; ++nt) {
            bf16x8 f0 = *(const bf16x8*)&wqff[((0 * 5 + nt) * 64 + l) * 8];
            bf16x8 f1 = *(const bf16x8*)&wqff[((1 * 5 + nt) * 64 + l) * 8];
            hacc[nt] = __builtin_amdgcn_mfma_f32_16x16x32_bf16(qf0, f0, hacc[nt], 0, 0, 0);
            hacc[nt] = __builtin_amdgcn_mfma_f32_16x16x32_bf16(qf1, f1, hacc[nt], 0, 0, 0);
        }
        #pragma unroll
        for (int nt = 0; nt < 5; ++nt) hv[nt] = hacc[nt][0];
    }

    // ---- W_eff = Wk + q (.) Wqk as 10 register B-frags (once/row) ----
    bf16x8 wf_[2][5];
    #pragma unroll
    for (int s = 0; s < 2; ++s) {
        float qa0 = (s == 0) ? q0.x  : q1.x,  qa1 = (s == 0) ? q0.y  : q1.y;
        float qa2 = (s == 0) ? q0.z  : q1.z,  qa3 = (s == 0) ? q0.w  : q1.w;
        float qb0 = (s == 0) ? q0b.x : q1b.x, qb1 = (s == 0) ? q0b.y : q1b.y;
        float qb2 = (s == 0) ? q0b.z : q1b.z, qb3 = (s == 0) ? q0b.w : q1b.w;
        #pragma unroll
        for (int nt = 0; nt < 5; ++nt) {
            bf16x8 wk = *(const bf16x8*)&w1f[((s * 5 + nt) * 64 + l) * 8];
            bf16x8 wq = *(const bf16x8*)&w1f[(((s + 2) * 5 + nt) * 64 + l) * 8];
            bf16x8 r;
            r[0] = (__bf16)fmaf(qa0, (float)wq[0], (float)wk[0]);
            r[1] = (__bf16)fmaf(qa1, (float)wq[1], (float)wk[1]);
            r[2] = (__bf16)fmaf(qa2, (float)wq[2], (float)wk[2]);
            r[3] = (__bf16)fmaf(qa3, (float)wq[3], (float)wk[3]);
            r[4] = (__bf16)fmaf(qb0, (float)wq[4], (float)wk[4]);
            r[5] = (__bf16)fmaf(qb1, (float)wq[5], (float)wk[5]);
            r[6] = (__bf16)fmaf(qb2, (float)wq[6], (float)wk[6]);
            r[7] = (__bf16)fmaf(qb3, (float)wq[7], (float)wk[7]);
            wf_[s][nt] = r;
        }
    }

    // softmax/PV accumulators (no-rescale: logits bounded, exp2 in [0.8,1.3])
    float s_part = 0.f;
    float4 o0 = {0,0,0,0}, o1 = o0, o2 = o0, o3 = o0;
    float e0_, e1_, e2_, e3_;

#define L1SIG(K0_, K1_, K2_, K3_, DST_) do {                               \
        f32x4 acc[5];                                                      \
        _Pragma("unroll")                                                  \
        for (int nt = 0; nt < 5; ++nt)                                     \
            acc[nt] = (f32x4){hv[nt], hv[nt], hv[nt], hv[nt]};             \
        bf16x8 av0 = pack8(K0_, K1_);                                      \
        bf16x8 av1 = pack8(K2_, K3_);                                      \
        _Pragma("unroll")                                                  \
        for (int nt = 0; nt < 5; ++nt) {                                   \
            acc[nt] = __builtin_amdgcn_mfma_f32_16x16x32_bf16(             \
                av0, wf_[0][nt], acc[nt], 0, 0, 0);                        \
            acc[nt] = __builtin_amdgcn_mfma_f32_16x16x32_bf16(             \
                av1, wf_[1][nt], acc[nt], 0, 0, 0);                        \
        }                                                                  \
        _Pragma("unroll")                                                  \
        for (int nt = 0; nt < 5; ++nt)                                     \
            _Pragma("unroll")                                              \
            for (int r = 0; r < 4; ++r) {                                  \
                float sg = frcp(1.f + fexp2(-acc[nt][r]));                 \
                (DST_)[(g4 * 4 + r) * 104 + nt * 16 + ln] = b16bits(sg);   \
            }                                                              \
    } while (0)

#define AFREAD(SRC_) do {                                                  \
        af0 = *(const bf16x8*)((SRC_) + ln * 104 + g4 * 8);                \
        af1 = *(const bf16x8*)((SRC_) + ln * 104 + 32 + g4 * 8);           \
        af2 = *(const bf16x8*)((SRC_) + ln * 104 + 64 + g4 * 8);           \
    } while (0)

#define L3E(tile_, r_, ER_) do {                                           \
        float p_ = w3v[0] * frcp(1.f + fexp2(-acc2[0][r_]))                \
                 + w3v[1] * frcp(1.f + fexp2(-acc2[1][r_]))                \
                 + w3v[2] * frcp(1.f + fexp2(-acc2[2][r_]));               \
        p_ += __shfl_xor(p_, 1); p_ += __shfl_xor(p_, 2);                  \
        p_ += __shfl_xor(p_, 4); p_ += __shfl_xor(p_, 8);                  \
        int trow_ = (tile_) * 16 + g4 * 4 + (r_);                          \
        ER_ = (trow_ < len)                                                \
            ? fexp2((p_ + b3v) * (0.125f * LOG2E)) : 0.f;                  \
    } while (0)

#define L2L3E(tile_) do {                                                  \
        f32x4 acc2[3];                                                     \
        _Pragma("unroll")                                                  \
        for (int nt = 0; nt < 3; ++nt)                                     \
            acc2[nt] = (f32x4){b2v[nt], b2v[nt], b2v[nt], b2v[nt]};        \
        _Pragma("unroll")                                                  \
        for (int nt = 0; nt < 3; ++nt) {                                   \
            bf16x8 w0_ = *(const bf16x8*)(w2f + ((0 * 3 + nt) * 64 + l) * 8); \
            bf16x8 w1_ = *(const bf16x8*)(w2f + ((1 * 3 + nt) * 64 + l) * 8); \
            bf16x8 w2_ = *(const bf16x8*)(w2f + ((2 * 3 + nt) * 64 + l) * 8); \
            acc2[nt] = __builtin_amdgcn_mfma_f32_16x16x32_bf16(af0, w0_, acc2[nt], 0, 0, 0); \
            acc2[nt] = __builtin_amdgcn_mfma_f32_16x16x32_bf16(af1, w1_, acc2[nt], 0, 0, 0); \
            acc2[nt] = __builtin_amdgcn_mfma_f32_16x16x32_bf16(af2, w2_, acc2[nt], 0, 0, 0); \
        }                                                                  \
        L3E(tile_, 0, e0_); L3E(tile_, 1, e1_);                            \
        L3E(tile_, 2, e2_); L3E(tile_, 3, e3_);                            \
    } while (0)

    // PV update: s += e's; route e[row=ln] to this lane with ONE bpermute
#define UPDATE(K0_, K1_, K2_, K3_) do {                                    \
        s_part += (e0_ + e1_) + (e2_ + e3_);                               \
        int rr_ = ln & 3;                                                  \
        float em_ = rr_ == 0 ? e0_ : rr_ == 1 ? e1_                        \
                  : rr_ == 2 ? e2_ : e3_;                                  \
        float pm_ = __shfl(em_, ((ln >> 2) << 4) + rr_);                   \
        o0.x = fmaf(pm_, K0_.x, o0.x); o0.y = fmaf(pm_, K0_.y, o0.y);      \
        o0.z = fmaf(pm_, K0_.z, o0.z); o0.w = fmaf(pm_, K0_.w, o0.w);      \
        o1.x = fmaf(pm_, K1_.x, o1.x); o1.y = fmaf(pm_, K1_.y, o1.y);      \
        o1.z = fmaf(pm_, K1_.z, o1.z); o1.w = fmaf(pm_, K1_.w, o1.w);      \
        o2.x = fmaf(pm_, K2_.x, o2.x); o2.y = fmaf(pm_, K2_.y, o2.y);      \
        o2.z = fmaf(pm_, K2_.z, o2.z); o2.w = fmaf(pm_, K2_.w, o2.w);      \
        o3.x = fmaf(pm_, K3_.x, o3.x); o3.y = fmaf(pm_, K3_.y, o3.y);      \
        o3.z = fmaf(pm_, K3_.z, o3.z); o3.w = fmaf(pm_, K3_.w, o3.w);      \
    } while (0)

    // ---- fused pipeline: L1SIG(it+1) hides AFREAD(it) LDS latency;
    //      keys(it) stay live through UPDATE(it), slot refilled after ----
    bf16x8 af0, af1, af2;
    L1SIG(A0, A1, A2, A3, buf0);           // h1(0); A = keys(0) stays live
    if (ntile > 1) {
        int it = 0;
        #pragma unroll 1
        while (it + 2 < ntile) {
            AFREAD(buf0);                  // h1(it)
            L1SIG(C0, C1, C2, C3, buf1);   // h1(it+1)
            L2L3E(it);
            UPDATE(A0, A1, A2, A3);        // keys(it) consumed
            LOADK(it + 2, A0, A1, A2, A3); // refill
            AFREAD(buf1);                  // h1(it+1)
            L1SIG(A0, A1, A2, A3, buf0);   // h1(it+2)
            L2L3E(it + 1);
            UPDATE(C0, C1, C2, C3);        // keys(it+1) consumed
            LOADK(it + 3, C0, C1, C2, C3); // over-prefetch clamped
            it += 2;
        }
        if (ntile - it == 2) {
            AFREAD(buf0);
            L1SIG(C0, C1, C2, C3, buf1);
            L2L3E(it);
            UPDATE(A0, A1, A2, A3);
            AFREAD(buf1);
            L2L3E(it + 1);
            UPDATE(C0, C1, C2, C3);
        } else {   // one tile left
            AFREAD(buf0);
            L2L3E(it);
            UPDATE(A0, A1, A2, A3);
        }
    } else {
        AFREAD(buf0);
        L2L3E(0);
        UPDATE(A0, A1, A2, A3);
    }
#undef LOADK
#undef L1SIG
#undef AFREAD
#undef L3E
#undef L2L3E
#undef UPDATE

    // ---- epilogue: normalize and reduce ----
    float s_tot = s_part;
    s_tot += __shfl_xor(s_tot, 16);
    s_tot += __shfl_xor(s_tot, 32);
    const float inv = frcp(s_tot);

#define RED16(x_) { x_ += __shfl_xor(x_, 1); x_ += __shfl_xor(x_, 2);      \
                    x_ += __shfl_xor(x_, 4); x_ += __shfl_xor(x_, 8); }
    RED16(o0.x) RED16(o0.y) RED16(o0.z) RED16(o0.w)
    RED16(o1.x) RED16(o1.y) RED16(o1.z) RED16(o1.w)
    RED16(o2.x) RED16(o2.y) RED16(o2.z) RED16(o2.w)
    RED16(o3.x) RED16(o3.y) RED16(o3.z) RED16(o3.w)
#undef RED16
    if (ln == 0) {
        float* od = olds[wid];
        od[g4 * 8 + 0] = o0.x; od[g4 * 8 + 1] = o0.y;
        od[g4 * 8 + 2] = o0.z; od[g4 * 8 + 3] = o0.w;
        od[g4 * 8 + 4] = o1.x; od[g4 * 8 + 5] = o1.y;
        od[g4 * 8 + 6] = o1.z; od[g4 * 8 + 7] = o1.w;
        od[32 + g4 * 8 + 0] = o2.x; od[32 + g4 * 8 + 1] = o2.y;
        od[32 + g4 * 8 + 2] = o2.z; od[32 + g4 * 8 + 3] = o2.w;
        od[32 + g4 * 8 + 4] = o3.x; od[32 + g4 * 8 + 5] = o3.y;
        od[32 + g4 * 8 + 6] = o3.z; od[32 + g4 * 8 + 7] = o3.w;
    }
    // same-wave LDS RAW: ds ops in order per wave (round-7-verified pattern)
    out[b * 64 + l] = olds[wid][l] * inv;
}

extern "C" void kernel_launch(void* const* d_in, const int* in_sizes, int n_in,
                              void* d_out, int out_size, void* d_ws, size_t ws_size,
                              hipStream_t stream) {
    const float* q    = (const float*)d_in[0];
    const float* keys = (const float*)d_in[1];
    const int*   kl   = (const int*)d_in[2];
    const float* W1   = (const float*)d_in[3];
    const float* b1   = (const float*)d_in[4];
    const float* W2   = (const float*)d_in[5];
    const float* b2   = (const float*)d_in[6];
    const float* W3   = (const float*)d_in[7];
    const float* b3   = (const float*)d_in[8];

    unsigned short* w1f  = (unsigned short*)d_ws;           // 10240 bf16
    unsigned short* w2f  = w1f + 10240;                     //  4608 bf16
    unsigned short* wqff = w2f + 4608;                      //  5120 bf16

    fold_weights<<<(19968 + 255) / 256, 256, 0, stream>>>(W1, W2, w1f, w2f, wqff);
    din_attn<<<B_ / 4, NT, 0, stream>>>(q, keys, kl, w1f, w2f, wqff, b1, b2,
                                        W3, b3, (float*)d_out);
}